// Round 5
// baseline (4452.367 us; speedup 1.0000x reference)
//
#include <hip/hip_runtime.h>

// LSTM_77893526880768: B=T=F=H=256.  256 independent row-chains, 255 steps.
//
// v5 recurrent architecture:
//   128 WGs = 16 row-groups x 8 col-groups, 256 threads (4 waves).
//   Weights live in LDS (v2/v4 showed the compiler will NOT keep a 128-VGPR
//   weight array resident: VGPR_Count=108 both times => scratch reloads from
//   an L2 that the acquire-poll's buffer_inv nuked every step = 8 us/step).
//   Per WG: 4 gates x 32 cols x 256 k bf16 = exactly 64 KB, staged once.
//   n-packing: wave w owns cols [cg*32+w*8, +8); n-tile 0 = {gate0,gate1}x8cols,
//   n-tile 1 = {gate2,gate3}x8cols  =>  each wave computes ALL 4 gates for its
//   8 cols; recombination is one shfl_xor(8) per acc element (no LDS exchange,
//   no bank conflicts). c in fp32 regs; elementwise duplicated in lane pairs.
//
//   Sync: v4-PROVEN protocol, unchanged: producer plain h stores ->
//   __threadfence (wbl2) -> __syncthreads -> tid0 RELEASE fetch_add; consumer
//   prefetches P into regs, tid0 ACQUIRE-spin (buffer_inv now harmless: weights
//   are in LDS, P is register-resident pre-poll, P/h lines have no L2 reuse).
//
// Workspace layout:
//   [0, 16K)        flags int[255][16] (memset 0 after precompute)
//   [16K, 16K+256K) Hbuf bf16[2][256][256]  (h double buffer; buf0 = h_0 = 0)
//                   (both overlay WxT, which is dead after precompute)
//   [0, 512K)       WxT bf16   (live only until precompute finishes)
//   [512K, 1M)      WhT bf16
//   [1M, 1M+4K)     bcat fp32
//   [1M+4K, ...)    P bf16  [t][rg][n][16] = 133,693,440 B

#define STEPS 255

typedef short bf16x8 __attribute__((ext_vector_type(8)));
typedef short bf16x4 __attribute__((ext_vector_type(4)));
typedef float f32x4  __attribute__((ext_vector_type(4)));

__device__ inline unsigned short f2bf(float f) {
  unsigned int u = __float_as_uint(f);
  unsigned int r = (u + 0x7FFFu + ((u >> 16) & 1u)) >> 16;  // RNE
  return (unsigned short)r;
}
__device__ inline float bf2f(unsigned short s) {
  return __uint_as_float(((unsigned int)s) << 16);
}
__device__ inline float sig_f(float x) {
  float e = exp2f(-1.442695041f * x);
  return __builtin_amdgcn_rcpf(1.0f + e);
}
__device__ inline float tanh_f(float x) {
  float e = exp2f(-2.885390082f * x);
  return 2.0f * __builtin_amdgcn_rcpf(1.0f + e) - 1.0f;
}

// ---------- prep: W transpose (W[k][j] fp32 -> WT[g*256+j][k] bf16) ----------
__global__ __launch_bounds__(256) void lstm_prep_w(
    const float* __restrict__ m0, const float* __restrict__ m1,
    const float* __restrict__ m2, const float* __restrict__ m3,
    const float* __restrict__ m4, const float* __restrict__ m5,
    const float* __restrict__ m6, const float* __restrict__ m7,
    unsigned short* __restrict__ WxT, unsigned short* __restrict__ WhT) {
  const float* mats[8] = {m0, m1, m2, m3, m4, m5, m6, m7};
  int mat = blockIdx.z;
  const float* W = mats[mat];
  unsigned short* out = (mat < 4 ? WxT : WhT) + (size_t)(mat & 3) * 256 * 256;
  int kblk = blockIdx.x * 32, jblk = blockIdx.y * 32;
  __shared__ float tile[32][33];
  int tx = threadIdx.x & 31, ty = threadIdx.x >> 5;
#pragma unroll
  for (int i = 0; i < 4; ++i) {
    int kk = ty + i * 8;
    tile[kk][tx] = W[(size_t)(kblk + kk) * 256 + jblk + tx];
  }
  __syncthreads();
#pragma unroll
  for (int i = 0; i < 4; ++i) {
    int jj = ty + i * 8;
    out[(size_t)(jblk + jj) * 256 + kblk + tx] = f2bf(tile[tx][jj]);
  }
}

// ---------- prep: bias fold ----------
__global__ void lstm_prep_b(
    const float* __restrict__ bx0, const float* __restrict__ bx1,
    const float* __restrict__ bx2, const float* __restrict__ bx3,
    const float* __restrict__ bh0, const float* __restrict__ bh1,
    const float* __restrict__ bh2, const float* __restrict__ bh3,
    float* __restrict__ bcat) {
  const float* bx[4] = {bx0, bx1, bx2, bx3};
  const float* bh[4] = {bh0, bh1, bh2, bh3};
  int i = blockIdx.x * 256 + threadIdx.x;
  int g = i >> 8, j = i & 255;
  bcat[i] = bx[g][j] + bh[g][j];
}

// ---------- precompute: P[t][rg][n][rl] = bcat[n] + sum_k x[r,t,k] Wx[k,n] ----------
__global__ __launch_bounds__(256, 1) void lstm_precompute(
    const float* __restrict__ x, const unsigned short* __restrict__ WxT,
    const float* __restrict__ bcat, unsigned short* __restrict__ P) {
  int t = blockIdx.x;
  int tid = threadIdx.x;
  int w = tid >> 6, lane = tid & 63, q = lane >> 4, cl = lane & 15;
  int rbase = w * 64;

  bf16x8 bfrag[8][4];
#pragma unroll
  for (int kt = 0; kt < 8; ++kt) {
    int k0 = kt * 32 + q * 8;
#pragma unroll
    for (int rt = 0; rt < 4; ++rt) {
      const float* xp = x + (((size_t)(rbase + rt * 16 + cl) * 256 + t) * 256 + k0);
      f32x4 lo = *(const f32x4*)xp;
      f32x4 hi = *(const f32x4*)(xp + 4);
      bf16x8 bv;
      bv[0] = (short)f2bf(lo[0]); bv[1] = (short)f2bf(lo[1]);
      bv[2] = (short)f2bf(lo[2]); bv[3] = (short)f2bf(lo[3]);
      bv[4] = (short)f2bf(hi[0]); bv[5] = (short)f2bf(hi[1]);
      bv[6] = (short)f2bf(hi[2]); bv[7] = (short)f2bf(hi[3]);
      bfrag[kt][rt] = bv;
    }
  }

  for (int nb = 0; nb < 16; ++nb) {
    int nblk = nb * 64;
    f32x4 acc[4][4];
#pragma unroll
    for (int a = 0; a < 4; ++a)
#pragma unroll
      for (int b = 0; b < 4; ++b) acc[a][b] = f32x4{0.f, 0.f, 0.f, 0.f};

#pragma unroll
    for (int kt = 0; kt < 8; ++kt) {
      int k0 = kt * 32 + q * 8;
      bf16x8 afrag[4];
#pragma unroll
      for (int mt = 0; mt < 4; ++mt)
        afrag[mt] = *(const bf16x8*)(WxT + (size_t)(nblk + mt * 16 + cl) * 256 + k0);
#pragma unroll
      for (int mt = 0; mt < 4; ++mt)
#pragma unroll
        for (int rt = 0; rt < 4; ++rt)
          acc[mt][rt] = __builtin_amdgcn_mfma_f32_16x16x32_bf16(
              afrag[mt], bfrag[kt][rt], acc[mt][rt], 0, 0, 0);
    }
#pragma unroll
    for (int mt = 0; mt < 4; ++mt) {
#pragma unroll
      for (int reg = 0; reg < 4; ++reg) {
        int n = nblk + mt * 16 + q * 4 + reg;
        float bb = bcat[n];
#pragma unroll
        for (int rt = 0; rt < 4; ++rt) {
          int rg_ = w * 4 + rt;
          P[(((size_t)t * 16 + rg_) * 1024 + n) * 16 + cl] = f2bf(acc[mt][rt][reg] + bb);
        }
      }
    }
  }
}

// ---------- recurrent v5: LDS-resident weights ----------
__global__ __launch_bounds__(256, 1) void lstm_recurrent(
    const unsigned short* __restrict__ WhT,
    const unsigned short* __restrict__ P,
    unsigned short* Hbuf, int* flags,
    float* __restrict__ out) {
  // Weight fragments, MFMA B-layout, exactly 64 KB (the whole LDS budget):
  // wlds[w][nt][kt][lane] : lane = q*16+cl holds Wh[n(nt,cl)][kt*32+q*8 .. +8]
  // where n(nt,cl) = gate(nt*2 + (cl>>3)) , col cg*32 + w*8 + (cl&7)
  __shared__ bf16x8 wlds[4][2][8][64];

  int tid = threadIdx.x;
  int w = tid >> 6, lane = tid & 63, q = lane >> 4, cl = lane & 15;
  int rg = blockIdx.x;  // rows [rg*16, rg*16+16)
  int cg = blockIdx.y;  // cols [cg*32, cg*32+32)
  int r0 = rg * 16;
  int jglob = cg * 32 + w * 8 + (cl & 7);  // this lane's elementwise column

  // ---- stage weights into LDS (once): 4096 16B-chunks, 16 per thread
  for (int i = 0; i < 16; ++i) {
    int idx = tid + i * 256;
    int sw = idx >> 10, snt = (idx >> 9) & 1, skt = (idx >> 6) & 7, sl = idx & 63;
    int sq = sl >> 4, scl = sl & 15;
    int gate = snt * 2 + (scl >> 3);
    int col = cg * 32 + sw * 8 + (scl & 7);
    int k0 = skt * 32 + sq * 8;
    (&wlds[0][0][0][0])[idx] = *(const bf16x8*)(WhT + (size_t)(gate * 256 + col) * 256 + k0);
  }
  __syncthreads();

  float creg[4] = {0.f, 0.f, 0.f, 0.f};  // c[r=r0+q*4+e][jglob] (dup in lane pairs)
  unsigned short* H0 = Hbuf;             // [256][256] bf16
  unsigned short* H1 = Hbuf + 65536;

  for (int t = 0; t < STEPS; ++t) {
    // P prefetch (independent of peers) before the flag wait — lands in regs.
    const unsigned short* Pt = P + ((size_t)t * 16 + rg) * 1024 * 16;
    bf16x4 pv[4];
#pragma unroll
    for (int g = 0; g < 4; ++g)
      pv[g] = *(const bf16x4*)(Pt + (size_t)(g * 256 + jglob) * 16 + q * 4);

    if (t > 0) {
      if (tid == 0) {
        const int* fp = flags + t * 16 + rg;  // == 8 when all peers finished t-1
        while (__hip_atomic_load(fp, __ATOMIC_ACQUIRE, __HIP_MEMORY_SCOPE_AGENT) < 8)
          __builtin_amdgcn_s_sleep(1);
      }
      __syncthreads();
    }

    // ---- A-frags: h_t rows (A[m=cl][k=q*8+j]); plain loads, post-acquire
    const unsigned short* Hr = ((t & 1) ? H1 : H0) + (size_t)(r0 + cl) * 256;
    bf16x8 afrag[8];
#pragma unroll
    for (int kt = 0; kt < 8; ++kt)
      afrag[kt] = *(const bf16x8*)(Hr + kt * 32 + q * 8);

    // ---- MFMA: 2 n-tiles ({i,f} and {g,o} x 8 cols) x 8 k-tiles, B from LDS
    f32x4 acc[2];
    acc[0] = f32x4{0.f, 0.f, 0.f, 0.f};
    acc[1] = f32x4{0.f, 0.f, 0.f, 0.f};
#pragma unroll
    for (int kt = 0; kt < 8; ++kt) {
#pragma unroll
      for (int nt = 0; nt < 2; ++nt)
        acc[nt] = __builtin_amdgcn_mfma_f32_16x16x32_bf16(
            afrag[kt], wlds[w][nt][kt][lane], acc[nt], 0, 0, 0);
    }

    // ---- elementwise: lane cl holds (cl<8 ? {i,g} : {f,o}) for col jglob;
    //      one shfl_xor(8) per acc element completes the gate set. Lane pairs
    //      (cl, cl^8) duplicate the computation; only cl<8 stores.
    unsigned short* Hw = ((t & 1) ? H0 : H1);
    bool last = (t == STEPS - 1);
    bool lo = (cl & 8) == 0;
#pragma unroll
    for (int e = 0; e < 4; ++e) {
      float own0 = acc[0][e], oth0 = __shfl_xor(own0, 8, 64);
      float own1 = acc[1][e], oth1 = __shfl_xor(own1, 8, 64);
      float pi = (lo ? own0 : oth0) + bf2f((unsigned short)pv[0][e]);
      float pf = (lo ? oth0 : own0) + bf2f((unsigned short)pv[1][e]);
      float pg = (lo ? own1 : oth1) + bf2f((unsigned short)pv[2][e]);
      float po = (lo ? oth1 : own1) + bf2f((unsigned short)pv[3][e]);
      float ig = sig_f(pi), fg = sig_f(pf), gg = tanh_f(pg), og = sig_f(po);
      float cn = fg * creg[e] + ig * gg;
      creg[e] = cn;
      float hn = og * tanh_f(cn);
      int r = r0 + q * 4 + e;
      if (lo) {
        if (!last) {
          Hw[(size_t)r * 256 + jglob] = f2bf(hn);  // plain store (v4-proven path)
        } else {
          out[(size_t)r * 256 + jglob] = hn;
          out[65536 + (size_t)r * 256 + jglob] = cn;
        }
      }
    }

    if (!last) {
      // v4-proven release sequence: wbl2+waitcnt, barrier, one RMW.
      __threadfence();
      __syncthreads();
      if (tid == 0)
        __hip_atomic_fetch_add(flags + (t + 1) * 16 + rg, 1,
                               __ATOMIC_RELEASE, __HIP_MEMORY_SCOPE_AGENT);
    }
  }
}

extern "C" void kernel_launch(void* const* d_in, const int* in_sizes, int n_in,
                              void* d_out, int out_size, void* d_ws, size_t ws_size,
                              hipStream_t stream) {
  const float* x = (const float*)d_in[0];
  const float* wx0 = (const float*)d_in[1];
  const float* wx1 = (const float*)d_in[5];
  const float* wx2 = (const float*)d_in[9];
  const float* wx3 = (const float*)d_in[13];
  const float* wh0 = (const float*)d_in[3];
  const float* wh1 = (const float*)d_in[7];
  const float* wh2 = (const float*)d_in[11];
  const float* wh3 = (const float*)d_in[15];
  const float* bx0 = (const float*)d_in[2];
  const float* bx1 = (const float*)d_in[6];
  const float* bx2 = (const float*)d_in[10];
  const float* bx3 = (const float*)d_in[14];
  const float* bh0 = (const float*)d_in[4];
  const float* bh1 = (const float*)d_in[8];
  const float* bh2 = (const float*)d_in[12];
  const float* bh3 = (const float*)d_in[16];

  char* ws = (char*)d_ws;
  unsigned short* WxT = (unsigned short*)(ws + 0);          // dead after precompute
  unsigned short* WhT = (unsigned short*)(ws + 524288);
  float* bcat = (float*)(ws + 1048576);
  unsigned short* P = (unsigned short*)(ws + 1052672);      // [t][rg][n][16] bf16
  int* flags = (int*)(ws + 0);                              // overlays WxT
  unsigned short* Hbuf = (unsigned short*)(ws + 16384);     // [2][256][256] bf16

  lstm_prep_w<<<dim3(8, 8, 8), 256, 0, stream>>>(wx0, wx1, wx2, wx3,
                                                 wh0, wh1, wh2, wh3, WxT, WhT);
  lstm_prep_b<<<4, 256, 0, stream>>>(bx0, bx1, bx2, bx3, bh0, bh1, bh2, bh3, bcat);
  lstm_precompute<<<255, 256, 0, stream>>>(x, WxT, bcat, P);
  hipMemsetAsync(ws, 0, 16384 + 262144, stream);  // flags + Hbuf (h_0 = 0)
  lstm_recurrent<<<dim3(16, 8), 256, 0, stream>>>(WhT, P, Hbuf, flags, (float*)d_out);
}

// Round 7
// 1613.036 us; speedup vs baseline: 2.7602x; 2.7602x over previous
//
#include <hip/hip_runtime.h>

// LSTM_77893526880768: B=T=F=H=256.  256 independent row-chains, 255 steps.
//
// v7 = v5 compute structure (LDS-resident weights, 0 bank conflicts) at 64 WGs
//      + v4's PROVEN release/acquire protocol with MINIMAL cache-op count.
//
// Evidence trail:
//   v4 (passed): threadfence by ALL threads (4 wbl2/WG/step) + ACQUIRE per
//     poll iteration (inv every ~64cyc while spinning) => 8.2us/step @64WG.
//   v5 (passed): same protocol @128WG => 16.7us/step. Cost = cache-wide ops
//     x WGs, serializing at each XCD's L2.
//   v3/v6 (failed): no wbl2 => flag can commit at its IC channel before the
//     h-stores commit at theirs (vmcnt-ack != IC-visibility; channels are
//     unordered). The wbl2/inv pair is NOT optional.
//   v7: exactly 1 wbl2 + 1 inv per WG per step:
//     producer: plain h stores -> __syncthreads (compiler's vmcnt(0) drain
//       puts all waves' stores in L2) -> tid0-only RELEASE fetch_add (its
//       lowering = buffer_wbl2 sc0 sc1 + waitcnt + IC RMW).
//     consumer: tid0 polls RELAXED/SYSTEM (per-access IC read, no inv storm;
//       v6 proved progress+visibility of IC flag reads) -> ONE acquire fence
//       (buffer_inv) -> __syncthreads -> plain h loads (wave0 misses to IC,
//       waves 1-3 hit refilled L1/L2).
//
//   64 WGs = 8 row-groups x 8 col-groups, 256 threads (4 waves).
//   WG: rows [rg*32,+32) x cols [cg*32,+32). LDS: 4 gates x 32 cols x 256 k
//   bf16 = 64 KB (v5-verified layout). Wave w owns cols [cg*32+w*8,+8);
//   n-tile 0 = {g0,g1}x8c, n-tile 1 = {g2,g3}x8c => all 4 gates per lane via
//   one shfl_xor(8). 2 row-tiles per wave; c in fp32 regs (creg[2][4]).
//
// Workspace layout:
//   [0, 16K)        flags int[255][8] (memset 0 after precompute)
//   [16K, 16K+256K) Hbuf bf16[2][256][256]  (h double buffer; buf0 = h_0 = 0)
//                   (both overlay WxT, which is dead after precompute)
//   [0, 512K)       WxT bf16   (live only until precompute finishes)
//   [512K, 1M)      WhT bf16
//   [1M, 1M+4K)     bcat fp32
//   [1M+4K, ...)    P bf16  [t][rg16][n][16] = 133,693,440 B

#define STEPS 255

typedef short bf16x8 __attribute__((ext_vector_type(8)));
typedef short bf16x4 __attribute__((ext_vector_type(4)));
typedef float f32x4  __attribute__((ext_vector_type(4)));

__device__ inline unsigned short f2bf(float f) {
  unsigned int u = __float_as_uint(f);
  unsigned int r = (u + 0x7FFFu + ((u >> 16) & 1u)) >> 16;  // RNE
  return (unsigned short)r;
}
__device__ inline float bf2f(unsigned short s) {
  return __uint_as_float(((unsigned int)s) << 16);
}
__device__ inline float sig_f(float x) {
  float e = exp2f(-1.442695041f * x);
  return __builtin_amdgcn_rcpf(1.0f + e);
}
__device__ inline float tanh_f(float x) {
  float e = exp2f(-2.885390082f * x);
  return 2.0f * __builtin_amdgcn_rcpf(1.0f + e) - 1.0f;
}

// ---------- prep: W transpose (W[k][j] fp32 -> WT[g*256+j][k] bf16) ----------
__global__ __launch_bounds__(256) void lstm_prep_w(
    const float* __restrict__ m0, const float* __restrict__ m1,
    const float* __restrict__ m2, const float* __restrict__ m3,
    const float* __restrict__ m4, const float* __restrict__ m5,
    const float* __restrict__ m6, const float* __restrict__ m7,
    unsigned short* __restrict__ WxT, unsigned short* __restrict__ WhT) {
  const float* mats[8] = {m0, m1, m2, m3, m4, m5, m6, m7};
  int mat = blockIdx.z;
  const float* W = mats[mat];
  unsigned short* out = (mat < 4 ? WxT : WhT) + (size_t)(mat & 3) * 256 * 256;
  int kblk = blockIdx.x * 32, jblk = blockIdx.y * 32;
  __shared__ float tile[32][33];
  int tx = threadIdx.x & 31, ty = threadIdx.x >> 5;
#pragma unroll
  for (int i = 0; i < 4; ++i) {
    int kk = ty + i * 8;
    tile[kk][tx] = W[(size_t)(kblk + kk) * 256 + jblk + tx];
  }
  __syncthreads();
#pragma unroll
  for (int i = 0; i < 4; ++i) {
    int jj = ty + i * 8;
    out[(size_t)(jblk + jj) * 256 + kblk + tx] = f2bf(tile[tx][jj]);
  }
}

// ---------- prep: bias fold ----------
__global__ void lstm_prep_b(
    const float* __restrict__ bx0, const float* __restrict__ bx1,
    const float* __restrict__ bx2, const float* __restrict__ bx3,
    const float* __restrict__ bh0, const float* __restrict__ bh1,
    const float* __restrict__ bh2, const float* __restrict__ bh3,
    float* __restrict__ bcat) {
  const float* bx[4] = {bx0, bx1, bx2, bx3};
  const float* bh[4] = {bh0, bh1, bh2, bh3};
  int i = blockIdx.x * 256 + threadIdx.x;
  int g = i >> 8, j = i & 255;
  bcat[i] = bx[g][j] + bh[g][j];
}

// ---------- precompute: P[t][rg16][n][rl] = bcat[n] + sum_k x[r,t,k] Wx[k,n] ----------
__global__ __launch_bounds__(256, 1) void lstm_precompute(
    const float* __restrict__ x, const unsigned short* __restrict__ WxT,
    const float* __restrict__ bcat, unsigned short* __restrict__ P) {
  int t = blockIdx.x;
  int tid = threadIdx.x;
  int w = tid >> 6, lane = tid & 63, q = lane >> 4, cl = lane & 15;
  int rbase = w * 64;

  bf16x8 bfrag[8][4];
#pragma unroll
  for (int kt = 0; kt < 8; ++kt) {
    int k0 = kt * 32 + q * 8;
#pragma unroll
    for (int rt = 0; rt < 4; ++rt) {
      const float* xp = x + (((size_t)(rbase + rt * 16 + cl) * 256 + t) * 256 + k0);
      f32x4 lo = *(const f32x4*)xp;
      f32x4 hi = *(const f32x4*)(xp + 4);
      bf16x8 bv;
      bv[0] = (short)f2bf(lo[0]); bv[1] = (short)f2bf(lo[1]);
      bv[2] = (short)f2bf(lo[2]); bv[3] = (short)f2bf(lo[3]);
      bv[4] = (short)f2bf(hi[0]); bv[5] = (short)f2bf(hi[1]);
      bv[6] = (short)f2bf(hi[2]); bv[7] = (short)f2bf(hi[3]);
      bfrag[kt][rt] = bv;
    }
  }

  for (int nb = 0; nb < 16; ++nb) {
    int nblk = nb * 64;
    f32x4 acc[4][4];
#pragma unroll
    for (int a = 0; a < 4; ++a)
#pragma unroll
      for (int b = 0; b < 4; ++b) acc[a][b] = f32x4{0.f, 0.f, 0.f, 0.f};

#pragma unroll
    for (int kt = 0; kt < 8; ++kt) {
      int k0 = kt * 32 + q * 8;
      bf16x8 afrag[4];
#pragma unroll
      for (int mt = 0; mt < 4; ++mt)
        afrag[mt] = *(const bf16x8*)(WxT + (size_t)(nblk + mt * 16 + cl) * 256 + k0);
#pragma unroll
      for (int mt = 0; mt < 4; ++mt)
#pragma unroll
        for (int rt = 0; rt < 4; ++rt)
          acc[mt][rt] = __builtin_amdgcn_mfma_f32_16x16x32_bf16(
              afrag[mt], bfrag[kt][rt], acc[mt][rt], 0, 0, 0);
    }
#pragma unroll
    for (int mt = 0; mt < 4; ++mt) {
#pragma unroll
      for (int reg = 0; reg < 4; ++reg) {
        int n = nblk + mt * 16 + q * 4 + reg;
        float bb = bcat[n];
#pragma unroll
        for (int rt = 0; rt < 4; ++rt) {
          int rg16 = w * 4 + rt;  // = r>>4
          P[(((size_t)t * 16 + rg16) * 1024 + n) * 16 + cl] = f2bf(acc[mt][rt][reg] + bb);
        }
      }
    }
  }
}

// ---------- recurrent v7: LDS weights + minimal-cache-op v4 protocol ----------
__global__ __launch_bounds__(256, 1) void lstm_recurrent(
    const unsigned short* __restrict__ WhT,
    const unsigned short* __restrict__ P,
    unsigned short* Hbuf, int* flags,
    float* __restrict__ out) {
  // Weight fragments, MFMA B-layout, exactly 64 KB (v5-verified):
  // wlds[w][nt][kt][lane] : lane = q*16+cl holds Wh[n(nt,cl)][kt*32+q*8 .. +8]
  // where n(nt,cl) = gate(nt*2 + (cl>>3)) , col cg*32 + w*8 + (cl&7)
  __shared__ bf16x8 wlds[4][2][8][64];

  int tid = threadIdx.x;
  int w = tid >> 6, lane = tid & 63, q = lane >> 4, cl = lane & 15;
  int rg = blockIdx.x;  // rows [rg*32, rg*32+32)
  int cg = blockIdx.y;  // cols [cg*32, cg*32+32)
  int r0 = rg * 32;
  int jglob = cg * 32 + w * 8 + (cl & 7);  // this lane's elementwise column

  // ---- stage weights into LDS (once): 4096 16B-chunks, 16 per thread
  for (int i = 0; i < 16; ++i) {
    int idx = tid + i * 256;
    int sw = idx >> 10, snt = (idx >> 9) & 1, skt = (idx >> 6) & 7, sl = idx & 63;
    int sq = sl >> 4, scl = sl & 15;
    int gate = snt * 2 + (scl >> 3);
    int col = cg * 32 + sw * 8 + (scl & 7);
    int k0 = skt * 32 + sq * 8;
    (&wlds[0][0][0][0])[idx] = *(const bf16x8*)(WhT + (size_t)(gate * 256 + col) * 256 + k0);
  }
  __syncthreads();

  float creg[2][4] = {{0.f, 0.f, 0.f, 0.f}, {0.f, 0.f, 0.f, 0.f}};
  unsigned short* H0 = Hbuf;             // [256][256] bf16
  unsigned short* H1 = Hbuf + 65536;

  for (int t = 0; t < STEPS; ++t) {
    // P prefetch (independent of peers) before the flag wait — lands in regs.
    bf16x4 pv[2][4];
#pragma unroll
    for (int rt = 0; rt < 2; ++rt) {
      int rg16 = rg * 2 + rt;
#pragma unroll
      for (int g = 0; g < 4; ++g)
        pv[rt][g] = *(const bf16x4*)(
            P + (((size_t)t * 16 + rg16) * 1024 + g * 256 + jglob) * 16 + q * 4);
    }

    if (t > 0) {
      if (tid == 0) {
        const int* fp = flags + t * 8 + rg;  // == 8 when all cg-peers finished t-1
        // RELAXED+SYSTEM poll: per-access IC read (v6-proven fresh), NO inv storm
        while (__hip_atomic_load(fp, __ATOMIC_RELAXED, __HIP_MEMORY_SCOPE_SYSTEM) < 8)
          __builtin_amdgcn_s_sleep(1);
        // ONE acquire fence: buffer_inv -> L1+L2 refill from IC for h loads
        __builtin_amdgcn_fence(__ATOMIC_ACQUIRE, "");
      }
      __syncthreads();
    }

    // ---- A-frags: h_t rows (A[m=cl][k=q*8+j]); plain loads post-inv
    //      (wave 0 misses to IC; waves 1-3 hit the refilled L1/L2)
    const unsigned short* Hb = (t & 1) ? H1 : H0;
    bf16x8 afrag[2][8];
#pragma unroll
    for (int rt = 0; rt < 2; ++rt)
#pragma unroll
      for (int kt = 0; kt < 8; ++kt)
        afrag[rt][kt] = *(const bf16x8*)(Hb + (size_t)(r0 + rt * 16 + cl) * 256 + kt * 32 + q * 8);

    // ---- MFMA: 2 row-tiles x 2 n-tiles ({i,f} and {g,o} x 8 cols) x 8 k-tiles
    f32x4 acc[2][2];
#pragma unroll
    for (int rt = 0; rt < 2; ++rt)
#pragma unroll
      for (int nt = 0; nt < 2; ++nt) acc[rt][nt] = f32x4{0.f, 0.f, 0.f, 0.f};
#pragma unroll
    for (int kt = 0; kt < 8; ++kt)
#pragma unroll
      for (int rt = 0; rt < 2; ++rt)
#pragma unroll
        for (int nt = 0; nt < 2; ++nt)
          acc[rt][nt] = __builtin_amdgcn_mfma_f32_16x16x32_bf16(
              afrag[rt][kt], wlds[w][nt][kt][lane], acc[rt][nt], 0, 0, 0);

    // ---- elementwise: lane cl holds (cl<8 ? {i,g} : {f,o}) for col jglob;
    //      one shfl_xor(8) per acc element completes the gate set.
    unsigned short* Hw = ((t & 1) ? H0 : H1);
    bool last = (t == STEPS - 1);
    bool lo = (cl & 8) == 0;
#pragma unroll
    for (int rt = 0; rt < 2; ++rt) {
#pragma unroll
      for (int e = 0; e < 4; ++e) {
        float own0 = acc[rt][0][e], oth0 = __shfl_xor(own0, 8, 64);
        float own1 = acc[rt][1][e], oth1 = __shfl_xor(own1, 8, 64);
        float pi = (lo ? own0 : oth0) + bf2f((unsigned short)pv[rt][0][e]);
        float pf = (lo ? oth0 : own0) + bf2f((unsigned short)pv[rt][1][e]);
        float pg = (lo ? own1 : oth1) + bf2f((unsigned short)pv[rt][2][e]);
        float po = (lo ? oth1 : own1) + bf2f((unsigned short)pv[rt][3][e]);
        float ig = sig_f(pi), fg = sig_f(pf), gg = tanh_f(pg), og = sig_f(po);
        float cn = fg * creg[rt][e] + ig * gg;
        creg[rt][e] = cn;
        float hn = og * tanh_f(cn);
        int r = r0 + rt * 16 + q * 4 + e;
        if (lo) {
          if (!last) {
            Hw[(size_t)r * 256 + jglob] = f2bf(hn);  // plain store (v4-proven)
          } else {
            out[(size_t)r * 256 + jglob] = hn;
            out[65536 + (size_t)r * 256 + jglob] = cn;
          }
        }
      }
    }

    if (!last) {
      // __syncthreads' documented vmcnt(0)-before-s_barrier drains every
      // wave's h stores into L2; tid0's RELEASE fetch_add then emits the ONE
      // buffer_wbl2 + waitcnt that publishes them to the IC before the flag.
      __syncthreads();
      if (tid == 0)
        __hip_atomic_fetch_add(flags + (t + 1) * 8 + rg, 1,
                               __ATOMIC_RELEASE, __HIP_MEMORY_SCOPE_SYSTEM);
    }
  }
}

extern "C" void kernel_launch(void* const* d_in, const int* in_sizes, int n_in,
                              void* d_out, int out_size, void* d_ws, size_t ws_size,
                              hipStream_t stream) {
  const float* x = (const float*)d_in[0];
  const float* wx0 = (const float*)d_in[1];
  const float* wx1 = (const float*)d_in[5];
  const float* wx2 = (const float*)d_in[9];
  const float* wx3 = (const float*)d_in[13];
  const float* wh0 = (const float*)d_in[3];
  const float* wh1 = (const float*)d_in[7];
  const float* wh2 = (const float*)d_in[11];
  const float* wh3 = (const float*)d_in[15];
  const float* bx0 = (const float*)d_in[2];
  const float* bx1 = (const float*)d_in[6];
  const float* bx2 = (const float*)d_in[10];
  const float* bx3 = (const float*)d_in[14];
  const float* bh0 = (const float*)d_in[4];
  const float* bh1 = (const float*)d_in[8];
  const float* bh2 = (const float*)d_in[12];
  const float* bh3 = (const float*)d_in[16];

  char* ws = (char*)d_ws;
  unsigned short* WxT = (unsigned short*)(ws + 0);          // dead after precompute
  unsigned short* WhT = (unsigned short*)(ws + 524288);
  float* bcat = (float*)(ws + 1048576);
  unsigned short* P = (unsigned short*)(ws + 1052672);      // [t][rg16][n][16] bf16
  int* flags = (int*)(ws + 0);                              // overlays WxT
  unsigned short* Hbuf = (unsigned short*)(ws + 16384);     // [2][256][256] bf16

  lstm_prep_w<<<dim3(8, 8, 8), 256, 0, stream>>>(wx0, wx1, wx2, wx3,
                                                 wh0, wh1, wh2, wh3, WxT, WhT);
  lstm_prep_b<<<4, 256, 0, stream>>>(bx0, bx1, bx2, bx3, bh0, bh1, bh2, bh3, bcat);
  lstm_precompute<<<255, 256, 0, stream>>>(x, WxT, bcat, P);
  hipMemsetAsync(ws, 0, 16384 + 262144, stream);  // flags + Hbuf (h_0 = 0)
  lstm_recurrent<<<dim3(8, 8), 256, 0, stream>>>(WhT, P, Hbuf, flags, (float*)d_out);
}

// Round 9
// 1459.726 us; speedup vs baseline: 3.0501x; 1.1050x over previous
//
#include <hip/hip_runtime.h>

// LSTM_77893526880768: B=T=F=H=256.  256 independent row-chains, 255 steps.
//
// v9 = v7 compute/protocol + runtime same-XCD fast path.
//
// Protocol evidence (8 rounds):
//   PASS: plain h loads preceded by buffer_inv (v4/v5/v7).  FAIL: every
//   "bypass" atomic-load consumer (v3 agent, v6 system, v8 system w/ proven
//   wbl2 producer) -> sc-bit loads can hit stale lines; inv is mandatory for
//   CROSS-XCD consumers.  Within one XCD all CUs share L2: plain stores are
//   L2-ack'd (proven: v4/v5/v7's wbl2-from-L2 protocol worked), so a peer's
//   sc0 (volatile) load probing the same L2 sees them -- no wbl2, no inv.
//   MI300/MI355 dispatch heuristic: XCD = linear_block_id % 8.  Grid (8,8),
//   id = rg + 8*cg  =>  all 8 cg-peers of rg on XCD rg.  v9 VERIFIES this at
//   runtime (HW_REG_XCC_ID exchange, one-time, full release/acquire) and
//   falls back to the exact v7 protocol per row-group if not co-located.
//   Row-groups never communicate with each other => correctness placement-
//   independent; only speed varies.
//
//   64 WGs = 8 rg x 8 cg, 256 threads.  LDS: 4g x 32c x 256k bf16 = 64 KB
//   weights (v5-verified layout).  All 4 gates per lane via shfl_xor(8).
//   c in fp32 regs.  t=0 skips the h read (h_0 = 0) => Hbuf needs no memset.
//
// Workspace layout:
//   [0, 16K)        flags int[255][8] + xcd_tab int[64] @ +8K (memset 0)
//   [16K, 16K+256K) Hbuf bf16[2][256][256] (uninit; never read before write)
//   [0, 512K)       WxT bf16   (live only until precompute finishes)
//   [512K, 1M)      WhT bf16
//   [1M, 1M+4K)     bcat fp32
//   [1M+4K, ...)    P bf16  [t][rg16][n][16] = 133,693,440 B

#define STEPS 255

typedef short bf16x8 __attribute__((ext_vector_type(8)));
typedef short bf16x4 __attribute__((ext_vector_type(4)));
typedef float f32x4  __attribute__((ext_vector_type(4)));

__device__ inline unsigned short f2bf(float f) {
  unsigned int u = __float_as_uint(f);
  unsigned int r = (u + 0x7FFFu + ((u >> 16) & 1u)) >> 16;  // RNE
  return (unsigned short)r;
}
__device__ inline float bf2f(unsigned short s) {
  return __uint_as_float(((unsigned int)s) << 16);
}
__device__ inline float sig_f(float x) {
  float e = exp2f(-1.442695041f * x);
  return __builtin_amdgcn_rcpf(1.0f + e);
}
__device__ inline float tanh_f(float x) {
  float e = exp2f(-2.885390082f * x);
  return 2.0f * __builtin_amdgcn_rcpf(1.0f + e) - 1.0f;
}

// ---------- prep: W transpose (W[k][j] fp32 -> WT[g*256+j][k] bf16) ----------
__global__ __launch_bounds__(256) void lstm_prep_w(
    const float* __restrict__ m0, const float* __restrict__ m1,
    const float* __restrict__ m2, const float* __restrict__ m3,
    const float* __restrict__ m4, const float* __restrict__ m5,
    const float* __restrict__ m6, const float* __restrict__ m7,
    unsigned short* __restrict__ WxT, unsigned short* __restrict__ WhT) {
  const float* mats[8] = {m0, m1, m2, m3, m4, m5, m6, m7};
  int mat = blockIdx.z;
  const float* W = mats[mat];
  unsigned short* out = (mat < 4 ? WxT : WhT) + (size_t)(mat & 3) * 256 * 256;
  int kblk = blockIdx.x * 32, jblk = blockIdx.y * 32;
  __shared__ float tile[32][33];
  int tx = threadIdx.x & 31, ty = threadIdx.x >> 5;
#pragma unroll
  for (int i = 0; i < 4; ++i) {
    int kk = ty + i * 8;
    tile[kk][tx] = W[(size_t)(kblk + kk) * 256 + jblk + tx];
  }
  __syncthreads();
#pragma unroll
  for (int i = 0; i < 4; ++i) {
    int jj = ty + i * 8;
    out[(size_t)(jblk + jj) * 256 + kblk + tx] = f2bf(tile[tx][jj]);
  }
}

// ---------- prep: bias fold ----------
__global__ void lstm_prep_b(
    const float* __restrict__ bx0, const float* __restrict__ bx1,
    const float* __restrict__ bx2, const float* __restrict__ bx3,
    const float* __restrict__ bh0, const float* __restrict__ bh1,
    const float* __restrict__ bh2, const float* __restrict__ bh3,
    float* __restrict__ bcat) {
  const float* bx[4] = {bx0, bx1, bx2, bx3};
  const float* bh[4] = {bh0, bh1, bh2, bh3};
  int i = blockIdx.x * 256 + threadIdx.x;
  int g = i >> 8, j = i & 255;
  bcat[i] = bx[g][j] + bh[g][j];
}

// ---------- precompute: P[t][rg16][n][rl] = bcat[n] + sum_k x[r,t,k] Wx[k,n] ----------
// grid (255, 2): blockIdx.y selects 8 of the 16 n-blocks (x-frags duplicated).
__global__ __launch_bounds__(256, 1) void lstm_precompute(
    const float* __restrict__ x, const unsigned short* __restrict__ WxT,
    const float* __restrict__ bcat, unsigned short* __restrict__ P) {
  int t = blockIdx.x;
  int tid = threadIdx.x;
  int w = tid >> 6, lane = tid & 63, q = lane >> 4, cl = lane & 15;
  int rbase = w * 64;

  bf16x8 bfrag[8][4];
#pragma unroll
  for (int kt = 0; kt < 8; ++kt) {
    int k0 = kt * 32 + q * 8;
#pragma unroll
    for (int rt = 0; rt < 4; ++rt) {
      const float* xp = x + (((size_t)(rbase + rt * 16 + cl) * 256 + t) * 256 + k0);
      f32x4 lo = *(const f32x4*)xp;
      f32x4 hi = *(const f32x4*)(xp + 4);
      bf16x8 bv;
      bv[0] = (short)f2bf(lo[0]); bv[1] = (short)f2bf(lo[1]);
      bv[2] = (short)f2bf(lo[2]); bv[3] = (short)f2bf(lo[3]);
      bv[4] = (short)f2bf(hi[0]); bv[5] = (short)f2bf(hi[1]);
      bv[6] = (short)f2bf(hi[2]); bv[7] = (short)f2bf(hi[3]);
      bfrag[kt][rt] = bv;
    }
  }

  for (int nbi = 0; nbi < 8; ++nbi) {
    int nblk = (blockIdx.y * 8 + nbi) * 64;
    f32x4 acc[4][4];
#pragma unroll
    for (int a = 0; a < 4; ++a)
#pragma unroll
      for (int b = 0; b < 4; ++b) acc[a][b] = f32x4{0.f, 0.f, 0.f, 0.f};

#pragma unroll
    for (int kt = 0; kt < 8; ++kt) {
      int k0 = kt * 32 + q * 8;
      bf16x8 afrag[4];
#pragma unroll
      for (int mt = 0; mt < 4; ++mt)
        afrag[mt] = *(const bf16x8*)(WxT + (size_t)(nblk + mt * 16 + cl) * 256 + k0);
#pragma unroll
      for (int mt = 0; mt < 4; ++mt)
#pragma unroll
        for (int rt = 0; rt < 4; ++rt)
          acc[mt][rt] = __builtin_amdgcn_mfma_f32_16x16x32_bf16(
              afrag[mt], bfrag[kt][rt], acc[mt][rt], 0, 0, 0);
    }
#pragma unroll
    for (int mt = 0; mt < 4; ++mt) {
#pragma unroll
      for (int reg = 0; reg < 4; ++reg) {
        int n = nblk + mt * 16 + q * 4 + reg;
        float bb = bcat[n];
#pragma unroll
        for (int rt = 0; rt < 4; ++rt) {
          int rg16 = w * 4 + rt;  // = r>>4
          P[(((size_t)t * 16 + rg16) * 1024 + n) * 16 + cl] = f2bf(acc[mt][rt][reg] + bb);
        }
      }
    }
  }
}

// ---------- recurrent v9: same-XCD fast path + v7 fallback ----------
__global__ __launch_bounds__(256, 1) void lstm_recurrent(
    const unsigned short* __restrict__ WhT,
    const unsigned short* __restrict__ P,
    unsigned short* Hbuf, int* flags, int* xcd_tab,
    float* __restrict__ out) {
  // Weight fragments, MFMA B-layout, exactly 64 KB (v5-verified):
  __shared__ bf16x8 wlds[4][2][8][64];

  int tid = threadIdx.x;
  int w = tid >> 6, lane = tid & 63, q = lane >> 4, cl = lane & 15;
  int rg = blockIdx.x;  // rows [rg*32, rg*32+32)
  int cg = blockIdx.y;  // cols [cg*32, cg*32+32)
  int r0 = rg * 32;
  int jglob = cg * 32 + w * 8 + (cl & 7);

  // ---- one-time XCD exchange (proven release/acquire; before weights stage)
  int* same_lds = (int*)&wlds[0][0][0][0];
  if (tid == 0) {
    unsigned xcc;
    asm volatile("s_getreg_b32 %0, hwreg(HW_REG_XCC_ID)" : "=s"(xcc));
    __hip_atomic_store(&xcd_tab[rg * 8 + cg], (int)xcc + 1,
                       __ATOMIC_RELEASE, __HIP_MEMORY_SCOPE_SYSTEM);
    int v0 = 0, samev = 1;
    for (int j = 0; j < 8; ++j) {
      int v;
      while ((v = __hip_atomic_load(&xcd_tab[rg * 8 + j],
                                    __ATOMIC_ACQUIRE, __HIP_MEMORY_SCOPE_SYSTEM)) == 0)
        __builtin_amdgcn_s_sleep(1);
      if (j == 0) v0 = v;
      else if (v != v0) samev = 0;
    }
    same_lds[0] = samev;
  }
  __syncthreads();
  int same = same_lds[0];
  __syncthreads();

  // ---- stage weights into LDS (once): 4096 16B-chunks, 16 per thread
  for (int i = 0; i < 16; ++i) {
    int idx = tid + i * 256;
    int sw = idx >> 10, snt = (idx >> 9) & 1, skt = (idx >> 6) & 7, sl = idx & 63;
    int sq = sl >> 4, scl = sl & 15;
    int gate = snt * 2 + (scl >> 3);
    int col = cg * 32 + sw * 8 + (scl & 7);
    int k0 = skt * 32 + sq * 8;
    (&wlds[0][0][0][0])[idx] = *(const bf16x8*)(WhT + (size_t)(gate * 256 + col) * 256 + k0);
  }
  __syncthreads();

  float creg[2][4] = {{0.f, 0.f, 0.f, 0.f}, {0.f, 0.f, 0.f, 0.f}};
  unsigned short* H0 = Hbuf;             // [256][256] bf16 (uninit; t=0 skips read)
  unsigned short* H1 = Hbuf + 65536;

  for (int t = 0; t < STEPS; ++t) {
    // P prefetch (independent of peers) before the flag wait — lands in regs.
    bf16x4 pv[2][4];
#pragma unroll
    for (int rt = 0; rt < 2; ++rt) {
      int rg16 = rg * 2 + rt;
#pragma unroll
      for (int g = 0; g < 4; ++g)
        pv[rt][g] = *(const bf16x4*)(
            P + (((size_t)t * 16 + rg16) * 1024 + g * 256 + jglob) * 16 + q * 4);
    }

    bf16x8 afrag[2][8];
    if (t > 0) {
      if (tid == 0) {
        const int* fp = flags + t * 8 + rg;  // == 8 when all cg-peers finished t-1
        while (__hip_atomic_load(fp, __ATOMIC_RELAXED, __HIP_MEMORY_SCOPE_SYSTEM) < 8)
          __builtin_amdgcn_s_sleep(1);
        if (!same)  // v7 slow path: one cache-wide acquire inv (cross-XCD peers)
          __builtin_amdgcn_fence(__ATOMIC_ACQUIRE, "");
      }
      __syncthreads();

      const unsigned short* Hb = (t & 1) ? H1 : H0;
      if (same) {
        // FAST: peers share this XCD's L2; volatile (sc0) loads bypass L1 and
        // probe the shared L2 where peers' plain stores are ack'd. No inv.
        const volatile bf16x8* Hv = (const volatile bf16x8*)Hb;
#pragma unroll
        for (int rt = 0; rt < 2; ++rt)
#pragma unroll
          for (int kt = 0; kt < 8; ++kt)
            afrag[rt][kt] = Hv[((size_t)(r0 + rt * 16 + cl) * 256 + kt * 32 + q * 8) >> 3];
      } else {
        // SLOW (v7-proven): plain loads post-inv.
#pragma unroll
        for (int rt = 0; rt < 2; ++rt)
#pragma unroll
          for (int kt = 0; kt < 8; ++kt)
            afrag[rt][kt] = *(const bf16x8*)(Hb + (size_t)(r0 + rt * 16 + cl) * 256 + kt * 32 + q * 8);
      }
    } else {
      // t = 0: h_0 = 0 -> no read, no wait (Hbuf may be uninitialized).
#pragma unroll
      for (int rt = 0; rt < 2; ++rt)
#pragma unroll
        for (int kt = 0; kt < 8; ++kt)
          afrag[rt][kt] = (bf16x8){0, 0, 0, 0, 0, 0, 0, 0};
    }

    // ---- MFMA: 2 row-tiles x 2 n-tiles ({i,f},{g,o} x 8 cols) x 8 k-tiles
    f32x4 acc[2][2];
#pragma unroll
    for (int rt = 0; rt < 2; ++rt)
#pragma unroll
      for (int nt = 0; nt < 2; ++nt) acc[rt][nt] = f32x4{0.f, 0.f, 0.f, 0.f};
#pragma unroll
    for (int kt = 0; kt < 8; ++kt)
#pragma unroll
      for (int rt = 0; rt < 2; ++rt)
#pragma unroll
        for (int nt = 0; nt < 2; ++nt)
          acc[rt][nt] = __builtin_amdgcn_mfma_f32_16x16x32_bf16(
              afrag[rt][kt], wlds[w][nt][kt][lane], acc[rt][nt], 0, 0, 0);

    // ---- elementwise: lane cl holds (cl<8 ? {i,g} : {f,o}); shfl_xor(8) pairs.
    unsigned short* Hw = ((t & 1) ? H0 : H1);
    bool last = (t == STEPS - 1);
    bool lo = (cl & 8) == 0;
#pragma unroll
    for (int rt = 0; rt < 2; ++rt) {
#pragma unroll
      for (int e = 0; e < 4; ++e) {
        float own0 = acc[rt][0][e], oth0 = __shfl_xor(own0, 8, 64);
        float own1 = acc[rt][1][e], oth1 = __shfl_xor(own1, 8, 64);
        float pi = (lo ? own0 : oth0) + bf2f((unsigned short)pv[rt][0][e]);
        float pf = (lo ? oth0 : own0) + bf2f((unsigned short)pv[rt][1][e]);
        float pg = (lo ? own1 : oth1) + bf2f((unsigned short)pv[rt][2][e]);
        float po = (lo ? oth1 : own1) + bf2f((unsigned short)pv[rt][3][e]);
        float ig = sig_f(pi), fg = sig_f(pf), gg = tanh_f(pg), og = sig_f(po);
        float cn = fg * creg[rt][e] + ig * gg;
        creg[rt][e] = cn;
        float hn = og * tanh_f(cn);
        int r = r0 + rt * 16 + q * 4 + e;
        if (lo) {
          if (!last) {
            Hw[(size_t)r * 256 + jglob] = f2bf(hn);  // plain store -> shared L2
          } else {
            out[(size_t)r * 256 + jglob] = hn;
            out[65536 + (size_t)r * 256 + jglob] = cn;
          }
        }
      }
    }

    if (!last) {
      // All waves' h stores are vmcnt-drained into L2 by this barrier.
      __syncthreads();
      if (tid == 0) {
        if (same)
          // FAST: peers consume from the shared L2; flag RMW (IC) needs no wbl2
          __hip_atomic_fetch_add(flags + (t + 1) * 8 + rg, 1,
                                 __ATOMIC_RELAXED, __HIP_MEMORY_SCOPE_SYSTEM);
        else
          // SLOW (v7-proven): RELEASE = wbl2 publishes L2-dirty h to IC first
          __hip_atomic_fetch_add(flags + (t + 1) * 8 + rg, 1,
                                 __ATOMIC_RELEASE, __HIP_MEMORY_SCOPE_SYSTEM);
      }
    }
  }
}

extern "C" void kernel_launch(void* const* d_in, const int* in_sizes, int n_in,
                              void* d_out, int out_size, void* d_ws, size_t ws_size,
                              hipStream_t stream) {
  const float* x = (const float*)d_in[0];
  const float* wx0 = (const float*)d_in[1];
  const float* wx1 = (const float*)d_in[5];
  const float* wx2 = (const float*)d_in[9];
  const float* wx3 = (const float*)d_in[13];
  const float* wh0 = (const float*)d_in[3];
  const float* wh1 = (const float*)d_in[7];
  const float* wh2 = (const float*)d_in[11];
  const float* wh3 = (const float*)d_in[15];
  const float* bx0 = (const float*)d_in[2];
  const float* bx1 = (const float*)d_in[6];
  const float* bx2 = (const float*)d_in[10];
  const float* bx3 = (const float*)d_in[14];
  const float* bh0 = (const float*)d_in[4];
  const float* bh1 = (const float*)d_in[8];
  const float* bh2 = (const float*)d_in[12];
  const float* bh3 = (const float*)d_in[16];

  char* ws = (char*)d_ws;
  unsigned short* WxT = (unsigned short*)(ws + 0);          // dead after precompute
  unsigned short* WhT = (unsigned short*)(ws + 524288);
  float* bcat = (float*)(ws + 1048576);
  unsigned short* P = (unsigned short*)(ws + 1052672);      // [t][rg16][n][16] bf16
  int* flags = (int*)(ws + 0);                              // overlays WxT
  int* xcd_tab = (int*)(ws + 8192);                         // 64 ints
  unsigned short* Hbuf = (unsigned short*)(ws + 16384);     // [2][256][256] bf16

  lstm_prep_w<<<dim3(8, 8, 8), 256, 0, stream>>>(wx0, wx1, wx2, wx3,
                                                 wh0, wh1, wh2, wh3, WxT, WhT);
  lstm_prep_b<<<4, 256, 0, stream>>>(bx0, bx1, bx2, bx3, bh0, bh1, bh2, bh3, bcat);
  lstm_precompute<<<dim3(255, 2), 256, 0, stream>>>(x, WxT, bcat, P);
  hipMemsetAsync(ws, 0, 16384, stream);  // flags + xcd_tab only (Hbuf never pre-read)
  lstm_recurrent<<<dim3(8, 8), 256, 0, stream>>>(WhT, P, Hbuf, flags, xcd_tab,
                                                 (float*)d_out);
}